// Round 1
// baseline (2233.713 us; speedup 1.0000x reference)
//
#include <hip/hip_runtime.h>
#include <math.h>

#define HH 256
#define WW 256
#define HWs 65536
#define DIMc 64
#define RK 32

__device__ inline float dot64(const float* __restrict__ w, const float* v) {
    const float4* w4 = (const float4*)w;
    float a = 0.f;
#pragma unroll
    for (int i = 0; i < 16; ++i) {
        float4 ww = w4[i];
        a += ww.x * v[4*i] + ww.y * v[4*i+1] + ww.z * v[4*i+2] + ww.w * v[4*i+3];
    }
    return a;
}
__device__ inline float dot32(const float* __restrict__ w, const float* v) {
    const float4* w4 = (const float4*)w;
    float a = 0.f;
#pragma unroll
    for (int i = 0; i < 8; ++i) {
        float4 ww = w4[i];
        a += ww.x * v[4*i] + ww.y * v[4*i+1] + ww.z * v[4*i+2] + ww.w * v[4*i+3];
    }
    return a;
}

// K1: per-pixel router + pointwise preprojections.
// Outputs: eIdx (expert), gVal (top-1 prob), qpre = q_w[e]@h1 (32ch), kvpre = kv_w[e]@h1 (64ch),
// where h1 = g * (p0_w[e] @ x).
__global__ __launch_bounds__(256) void k_router(
    const float* __restrict__ x,
    const float* __restrict__ rw, const float* __restrict__ rb,
    const float* __restrict__ p0w, const float* __restrict__ qw, const float* __restrict__ kvw,
    int* __restrict__ eIdx, float* __restrict__ gVal,
    float* __restrict__ qpre, float* __restrict__ kvpre)
{
    int p = blockIdx.x * blockDim.x + threadIdx.x;   // [0, B*HW)
    int b = p >> 16;
    int hw = p & 0xFFFF;

    const float* xb = x + ((size_t)b * DIMc) * HWs + hw;
    float xr[DIMc];
#pragma unroll
    for (int c = 0; c < DIMc; ++c) xr[c] = xb[(size_t)c * HWs];

    float l[4];
#pragma unroll
    for (int e = 0; e < 4; ++e) l[e] = rb[e] + dot64(&rw[e * DIMc], xr);

    float m = fmaxf(fmaxf(l[0], l[1]), fmaxf(l[2], l[3]));
    int e = (l[0] == m) ? 0 : (l[1] == m) ? 1 : (l[2] == m) ? 2 : 3;
    float s = expf(l[0]-m) + expf(l[1]-m) + expf(l[2]-m) + expf(l[3]-m);
    float g = 1.0f / s;   // prob of argmax: exp(0)/sum
    eIdx[p] = e;
    gVal[p] = g;

    float h1[RK];
    const float* w0 = p0w + e * RK * DIMc;
    for (int r = 0; r < RK; ++r) h1[r] = g * dot64(&w0[r * DIMc], xr);

    const float* wq = qw + e * RK * RK;
    for (int r = 0; r < RK; ++r)
        qpre[((size_t)(b * RK + r)) * HWs + hw] = dot32(&wq[r * RK], h1);

    const float* wk = kvw + e * 2 * RK * RK;
    for (int r = 0; r < 2 * RK; ++r)
        kvpre[((size_t)(b * 2 * RK + r)) * HWs + hw] = dot32(&wk[r * RK], h1);
}

// K2: one block (64 threads) per 8x8 patch. Per channel: sparse dw3 (q, all experts),
// sparse dw7 (k all experts, v own expert), 8x8 circular conv for own expert.
// Then per-thread: LN over 32ch, *ln_w+ln_b, *v, fp conv, silu gate from shared, p2, residual, out_w conv.
__global__ __launch_bounds__(64) void k_patch(
    const float* __restrict__ x, const float* __restrict__ shr,
    const int* __restrict__ eIdx, const float* __restrict__ gVal,
    const float* __restrict__ qpre, const float* __restrict__ kvpre,
    const float* __restrict__ p1w,
    const float* __restrict__ qdw, const float* __restrict__ qdb,
    const float* __restrict__ kvdw, const float* __restrict__ kvdb,
    const float* __restrict__ lnw, const float* __restrict__ lnb,
    const float* __restrict__ fpw, const float* __restrict__ fpb,
    const float* __restrict__ p2w,
    const float* __restrict__ outw, const float* __restrict__ outb,
    float* __restrict__ out)
{
    __shared__ int   eh[196];        // e over 14x14 halo (-3..10), -1 = outside image
    __shared__ float qh[100];        // qpre channel plane over 10x10 halo (-1..8)
    __shared__ float kh[196];        // kvpre k-channel plane 14x14
    __shared__ float vh[196];        // kvpre v-channel plane 14x14
    __shared__ float qA[256];        // q[expert][pixel] this channel
    __shared__ float kA[256];        // k[expert][pixel] this channel
    __shared__ float wq3[36];        // q dw weights, 4 experts x 9
    __shared__ float wk7[196];       // k dw weights, 4 experts x 49
    __shared__ float wv7[196];       // v dw weights, 4 experts x 49
    __shared__ float oOwn[64*33];    // circular-conv output [pixel][ch] (padded stride)
    __shared__ float vOwn[64*33];    // v (own expert) [pixel][ch]

    const int t = threadIdx.x;
    const int bid = blockIdx.x;
    const int b  = bid >> 10;        // 32*32 = 1024 patches per image
    const int pp = bid & 1023;
    const int py = pp >> 5, px = pp & 31;
    const int y0 = py * 8, x0 = px * 8;
    const int ly = t >> 3, lx = t & 7;
    const int gy = y0 + ly, gx = x0 + lx;
    const int hw = gy * WW + gx;
    const size_t base = (size_t)b * HWs;

    for (int j = t; j < 196; j += 64) {
        int yy = y0 - 3 + j / 14;
        int xx = x0 - 3 + j % 14;
        int v = -1;
        if (yy >= 0 && yy < HH && xx >= 0 && xx < WW) v = eIdx[base + yy * WW + xx];
        eh[j] = v;
    }
    __syncthreads();
    const int ep = eh[(ly + 3) * 14 + (lx + 3)];

    for (int c = 0; c < RK; ++c) {
        // ---- stage planes + weights for this channel ----
        for (int j = t; j < 196; j += 64) {
            int yy = y0 - 3 + j / 14;
            int xx = x0 - 3 + j % 14;
            float kv_ = 0.f, vv_ = 0.f;
            if (yy >= 0 && yy < HH && xx >= 0 && xx < WW) {
                size_t o1 = ((size_t)(b * 64 + c)) * HWs + yy * WW + xx;
                kv_ = kvpre[o1];
                vv_ = kvpre[o1 + (size_t)32 * HWs];
            }
            kh[j] = kv_; vh[j] = vv_;
        }
        for (int j = t; j < 100; j += 64) {
            int yy = y0 - 1 + j / 10;
            int xx = x0 - 1 + j % 10;
            float qv = 0.f;
            if (yy >= 0 && yy < HH && xx >= 0 && xx < WW)
                qv = qpre[((size_t)(b * RK + c)) * HWs + yy * WW + xx];
            qh[j] = qv;
        }
        if (t < 36) wq3[t] = qdw[(t / 9) * RK * 9 + c * 9 + (t % 9)];
        for (int j = t; j < 196; j += 64) {
            int i = j / 49, kk = j % 49;
            wk7[j] = kvdw[((size_t)(i * 64 + c)) * 49 + kk];
            wv7[j] = kvdw[((size_t)(i * 64 + 32 + c)) * 49 + kk];
        }
        __syncthreads();

        // ---- dw3: q for all experts at this pixel ----
        float qa0 = qdb[0*RK+c], qa1 = qdb[1*RK+c], qa2 = qdb[2*RK+c], qa3 = qdb[3*RK+c];
#pragma unroll
        for (int dy = 0; dy < 3; ++dy)
#pragma unroll
        for (int dx = 0; dx < 3; ++dx) {
            int ie = eh[(ly + dy) * 14 + (lx + dx)];
            if (ie >= 0) {
                float wv = wq3[ie * 9 + dy * 3 + dx] * qh[(ly + dy) * 10 + (lx + dx)];
                qa0 += (ie == 0) ? wv : 0.f;
                qa1 += (ie == 1) ? wv : 0.f;
                qa2 += (ie == 2) ? wv : 0.f;
                qa3 += (ie == 3) ? wv : 0.f;
            }
        }
        qA[0*64+t] = qa0; qA[1*64+t] = qa1; qA[2*64+t] = qa2; qA[3*64+t] = qa3;

        // ---- dw7: k for all experts, v for own expert ----
        float ka0 = kvdb[0*64+c], ka1 = kvdb[1*64+c], ka2 = kvdb[2*64+c], ka3 = kvdb[3*64+c];
        float va = kvdb[ep * 64 + 32 + c];
#pragma unroll
        for (int dy = 0; dy < 7; ++dy)
#pragma unroll
        for (int dx = 0; dx < 7; ++dx) {
            int ie = eh[(ly + dy) * 14 + (lx + dx)];
            if (ie >= 0) {
                int off = dy * 7 + dx;
                float kval = kh[(ly + dy) * 14 + (lx + dx)];
                float wv = wk7[ie * 49 + off] * kval;
                ka0 += (ie == 0) ? wv : 0.f;
                ka1 += (ie == 1) ? wv : 0.f;
                ka2 += (ie == 2) ? wv : 0.f;
                ka3 += (ie == 3) ? wv : 0.f;
                if (ie == ep) va += wv7[ep * 49 + off] * vh[(ly + dy) * 14 + (lx + dx)];
            }
        }
        kA[0*64+t] = ka0; kA[1*64+t] = ka1; kA[2*64+t] = ka2; kA[3*64+t] = ka3;
        vOwn[t * 33 + c] = va;
        __syncthreads();

        // ---- 8x8 circular convolution, own expert only ----
        const float* qrow = &qA[ep * 64];
        const float* krow = &kA[ep * 64];
        float oc = 0.f;
#pragma unroll
        for (int sy = 0; sy < 8; ++sy) {
            int ky = ((ly - sy) & 7) * 8;
#pragma unroll
            for (int sx = 0; sx < 8; ++sx)
                oc += qrow[sy * 8 + sx] * krow[ky + ((lx - sx) & 7)];
        }
        oOwn[t * 33 + c] = oc;
        __syncthreads();   // protect planes/qA/kA before next channel overwrites
    }

    // ---- epilogue (all per-pixel) ----
    float o[RK], vv[RK];
#pragma unroll
    for (int c = 0; c < RK; ++c) { o[c] = oOwn[t * 33 + c]; vv[c] = vOwn[t * 33 + c]; }

    float mu = 0.f;
#pragma unroll
    for (int c = 0; c < RK; ++c) mu += o[c];
    mu *= (1.0f / RK);
    float var = 0.f;
#pragma unroll
    for (int c = 0; c < RK; ++c) { float d = o[c] - mu; var += d * d; }
    var *= (1.0f / RK);
    float inv = 1.0f / sqrtf(var + 1e-5f);

    float tt[RK];
#pragma unroll
    for (int c = 0; c < RK; ++c)
        tt[c] = ((o[c] - mu) * inv * lnw[ep * RK + c] + lnb[ep * RK + c]) * vv[c];

    float g = gVal[base + hw];

    float sv[DIMc];
#pragma unroll
    for (int c = 0; c < DIMc; ++c) sv[c] = shr[((size_t)(b * DIMc + c)) * HWs + hw];

    float u[RK];
    for (int r = 0; r < RK; ++r) {
        float z = g * dot64(&p1w[(ep * RK + r) * DIMc], sv);
        float gate = z / (1.f + expf(-z));                       // silu
        float bdy = fpb[ep * RK + r] + dot32(&fpw[(ep * RK + r) * RK], tt);
        u[r] = bdy * gate;
    }

    float comb[DIMc];
    for (int oo = 0; oo < DIMc; ++oo) {
        float a = dot32(&p2w[(ep * DIMc + oo) * RK], u);
        float xv = x[((size_t)(b * DIMc + oo)) * HWs + hw];
        comb[oo] = g * a + g * g * xv;   // mask*(p2@(body*gate) + mx)
    }

    for (int oo = 0; oo < DIMc; ++oo) {
        float a = outb[oo] + dot64(&outw[oo * DIMc], comb);
        out[((size_t)(b * DIMc + oo)) * HWs + hw] = a;
    }
}

extern "C" void kernel_launch(void* const* d_in, const int* in_sizes, int n_in,
                              void* d_out, int out_size, void* d_ws, size_t ws_size,
                              hipStream_t stream) {
    const float* x    = (const float*)d_in[0];
    const float* shr  = (const float*)d_in[1];
    const float* rw   = (const float*)d_in[2];
    const float* rb_  = (const float*)d_in[3];
    const float* p0w  = (const float*)d_in[4];
    const float* p1w  = (const float*)d_in[5];
    const float* p2w  = (const float*)d_in[6];
    const float* qw   = (const float*)d_in[7];
    const float* qdw  = (const float*)d_in[8];
    const float* qdb  = (const float*)d_in[9];
    const float* kvw  = (const float*)d_in[10];
    const float* kvdw = (const float*)d_in[11];
    const float* kvdb = (const float*)d_in[12];
    const float* lnw  = (const float*)d_in[13];
    const float* lnb  = (const float*)d_in[14];
    const float* fpw  = (const float*)d_in[15];
    const float* fpb  = (const float*)d_in[16];
    const float* outw = (const float*)d_in[17];
    const float* outb = (const float*)d_in[18];
    float* out = (float*)d_out;

    const int N = 4 * HWs;   // B*H*W
    char* ws = (char*)d_ws;
    int*   eIdx  = (int*)ws;            ws += (size_t)N * sizeof(int);
    float* gV    = (float*)ws;          ws += (size_t)N * sizeof(float);
    float* qpre  = (float*)ws;          ws += (size_t)N * RK * sizeof(float);
    float* kvpre = (float*)ws;          ws += (size_t)N * 2 * RK * sizeof(float);

    k_router<<<N / 256, 256, 0, stream>>>(x, rw, rb_, p0w, qw, kvw, eIdx, gV, qpre, kvpre);
    k_patch<<<4 * 32 * 32, 64, 0, stream>>>(x, shr, eIdx, gV, qpre, kvpre,
                                            p1w, qdw, qdb, kvdw, kvdb,
                                            lnw, lnb, fpw, fpb, p2w, outw, outb, out);
}

// Round 2
// 1534.999 us; speedup vs baseline: 1.4552x; 1.4552x over previous
//
#include <hip/hip_runtime.h>
#include <math.h>

#define HH 256
#define WW 256
#define HWs 65536
#define DIMc 64
#define RK 32

__device__ inline float dot64(const float* __restrict__ w, const float* v) {
    const float4* w4 = (const float4*)w;
    float a = 0.f;
#pragma unroll
    for (int i = 0; i < 16; ++i) {
        float4 ww = w4[i];
        a += ww.x * v[4*i] + ww.y * v[4*i+1] + ww.z * v[4*i+2] + ww.w * v[4*i+3];
    }
    return a;
}
__device__ inline float dot32(const float* __restrict__ w, const float* v) {
    const float4* w4 = (const float4*)w;
    float a = 0.f;
#pragma unroll
    for (int i = 0; i < 8; ++i) {
        float4 ww = w4[i];
        a += ww.x * v[4*i] + ww.y * v[4*i+1] + ww.z * v[4*i+2] + ww.w * v[4*i+3];
    }
    return a;
}

// K1: per-pixel router + pointwise preprojections, expert weights staged in LDS.
__global__ __launch_bounds__(256) void k_router(
    const float* __restrict__ x,
    const float* __restrict__ rw, const float* __restrict__ rb,
    const float* __restrict__ p0w, const float* __restrict__ qw, const float* __restrict__ kvw,
    int* __restrict__ eIdx, float* __restrict__ gVal,
    float* __restrict__ qpre, float* __restrict__ kvpre)
{
    // phase A: rw[256] @0, p0w[8192] @256, qw[4096] @8448  (50176 B)
    // phase B: kvw[8192] @0
    __shared__ float wl[12544];
    const int tid = threadIdx.x;
    const int p = blockIdx.x * 256 + tid;   // [0, B*HW)
    const int b = p >> 16;
    const int hw = p & 0xFFFF;

    for (int i = tid; i < 256;  i += 256) wl[i] = rw[i];
    for (int i = tid; i < 8192; i += 256) wl[256 + i] = p0w[i];
    for (int i = tid; i < 4096; i += 256) wl[8448 + i] = qw[i];
    __syncthreads();

    const float* xb = x + ((size_t)b * DIMc) * HWs + hw;
    float xr[DIMc];
#pragma unroll
    for (int c = 0; c < DIMc; ++c) xr[c] = xb[(size_t)c * HWs];

    float l[4];
#pragma unroll
    for (int e = 0; e < 4; ++e) l[e] = rb[e] + dot64(&wl[e * DIMc], xr);

    float m = fmaxf(fmaxf(l[0], l[1]), fmaxf(l[2], l[3]));
    int e = (l[0] == m) ? 0 : (l[1] == m) ? 1 : (l[2] == m) ? 2 : 3;
    float s = expf(l[0]-m) + expf(l[1]-m) + expf(l[2]-m) + expf(l[3]-m);
    float g = 1.0f / s;
    eIdx[p] = e;
    gVal[p] = g;

    float h1[RK];
    const float* w0 = &wl[256 + e * RK * DIMc];
#pragma unroll
    for (int r = 0; r < RK; ++r) h1[r] = g * dot64(&w0[r * DIMc], xr);

    const float* wq = &wl[8448 + e * RK * RK];
#pragma unroll
    for (int r = 0; r < RK; ++r)
        qpre[((size_t)(b * RK + r)) * HWs + hw] = dot32(&wq[r * RK], h1);

    __syncthreads();
    for (int i = tid; i < 8192; i += 256) wl[i] = kvw[i];
    __syncthreads();

    const float* wk = &wl[e * 2 * RK * RK];
#pragma unroll
    for (int r = 0; r < 2 * RK; ++r)
        kvpre[((size_t)(b * 2 * RK + r)) * HWs + hw] = dot32(&wk[r * RK], h1);
}

// K2: one 256-thread block per 8x8 patch; 4 channels in flight (cq = tid>>6).
__global__ __launch_bounds__(256) void k_patch(
    const float* __restrict__ x, const float* __restrict__ shr,
    const int* __restrict__ eIdx, const float* __restrict__ gVal,
    const float* __restrict__ qpre, const float* __restrict__ kvpre,
    const float* __restrict__ p1w,
    const float* __restrict__ qdw, const float* __restrict__ qdb,
    const float* __restrict__ kvdw, const float* __restrict__ kvdb,
    const float* __restrict__ lnw, const float* __restrict__ lnb,
    const float* __restrict__ fpw, const float* __restrict__ fpb,
    const float* __restrict__ p2w,
    const float* __restrict__ outw, const float* __restrict__ outb,
    float* __restrict__ out)
{
    __shared__ int   eh[210];        // 14x14 halo (-3..10), stride 15, -1 = outside
    __shared__ float oOwn[64*33];    // circ-conv output [pixel][ch]
    __shared__ float vOwn[64*33];    // v (own expert) [pixel][ch]
    __shared__ float pool[6272];     // aliased: main-loop planes | epilogue buffers

    // main-loop layout in pool (per cq channel):
    float* kh  = pool;          // 4 x 210 (14x14 stride 15)
    float* vh  = pool + 840;    // 4 x 210
    float* qh  = pool + 1680;   // 4 x 110 (10x10 stride 11)
    float* qA  = pool + 2120;   // 4 x [expert][64]
    float* kA  = pool + 3144;   // 4 x [expert][64]
    float* wq3 = pool + 4168;   // 4 x 36
    float* wk7 = pool + 4312;   // 4 x 196
    float* wv7 = pool + 5096;   // 4 x 196

    const int tid = threadIdx.x;
    const int cq = tid >> 6;
    const int t  = tid & 63;
    const int bid = blockIdx.x;
    const int b  = bid >> 10;
    const int pp = bid & 1023;
    const int py = pp >> 5, px = pp & 31;
    const int y0 = py * 8, x0 = px * 8;
    const int ly = t >> 3, lx = t & 7;
    const int gy = y0 + ly, gx = x0 + lx;
    const int hw = gy * WW + gx;
    const size_t base = (size_t)b * HWs;

    for (int j = tid; j < 196; j += 256) {
        int r = j / 14, cc = j % 14;
        int yy = y0 - 3 + r, xx = x0 - 3 + cc;
        int v = -1;
        if ((unsigned)yy < HH && (unsigned)xx < WW) v = eIdx[base + yy * WW + xx];
        eh[r * 15 + cc] = v;
    }
    __syncthreads();
    const int ep = eh[(ly + 3) * 15 + (lx + 3)];

    for (int ch = 0; ch < 8; ++ch) {
        const int c = ch * 4 + cq;
        // ---- stage planes + weights for this channel ----
        for (int j = t; j < 196; j += 64) {
            int r = j / 14, cc = j % 14;
            int yy = y0 - 3 + r, xx = x0 - 3 + cc;
            float kv_ = 0.f, vv_ = 0.f;
            if ((unsigned)yy < HH && (unsigned)xx < WW) {
                size_t o1 = ((size_t)(b * 64 + c)) * HWs + yy * WW + xx;
                kv_ = kvpre[o1];
                vv_ = kvpre[o1 + (size_t)32 * HWs];
            }
            kh[cq * 210 + r * 15 + cc] = kv_;
            vh[cq * 210 + r * 15 + cc] = vv_;
        }
        for (int j = t; j < 100; j += 64) {
            int r = j / 10, cc = j % 10;
            int yy = y0 - 1 + r, xx = x0 - 1 + cc;
            float qv = 0.f;
            if ((unsigned)yy < HH && (unsigned)xx < WW)
                qv = qpre[((size_t)(b * RK + c)) * HWs + yy * WW + xx];
            qh[cq * 110 + r * 11 + cc] = qv;
        }
        if (t < 36) wq3[cq * 36 + t] = qdw[(t / 9) * RK * 9 + c * 9 + (t % 9)];
        for (int j = t; j < 196; j += 64) {
            int i = j / 49, kk = j % 49;
            wk7[cq * 196 + j] = kvdw[((size_t)(i * 64 + c)) * 49 + kk];
            wv7[cq * 196 + j] = kvdw[((size_t)(i * 64 + 32 + c)) * 49 + kk];
        }
        __syncthreads();

        // ---- dw3: q for all experts at this pixel (halo origin -1 -> eh offset +2) ----
        const float* qhc = &qh[cq * 110];
        float qa0 = qdb[0*RK+c], qa1 = qdb[1*RK+c], qa2 = qdb[2*RK+c], qa3 = qdb[3*RK+c];
#pragma unroll
        for (int dy = 0; dy < 3; ++dy)
#pragma unroll
        for (int dx = 0; dx < 3; ++dx) {
            int ie = eh[(ly + dy + 2) * 15 + (lx + dx + 2)];
            if (ie >= 0) {
                float wv = wq3[cq * 36 + ie * 9 + dy * 3 + dx] * qhc[(ly + dy) * 11 + (lx + dx)];
                qa0 += (ie == 0) ? wv : 0.f;
                qa1 += (ie == 1) ? wv : 0.f;
                qa2 += (ie == 2) ? wv : 0.f;
                qa3 += (ie == 3) ? wv : 0.f;
            }
        }
        qA[cq*256 + 0*64+t] = qa0; qA[cq*256 + 1*64+t] = qa1;
        qA[cq*256 + 2*64+t] = qa2; qA[cq*256 + 3*64+t] = qa3;

        // ---- dw7: k for all experts, v for own expert ----
        const float* khc = &kh[cq * 210];
        const float* vhc = &vh[cq * 210];
        float ka0 = kvdb[0*64+c], ka1 = kvdb[1*64+c], ka2 = kvdb[2*64+c], ka3 = kvdb[3*64+c];
        float va = kvdb[ep * 64 + 32 + c];
#pragma unroll
        for (int dy = 0; dy < 7; ++dy)
#pragma unroll
        for (int dx = 0; dx < 7; ++dx) {
            int ie = eh[(ly + dy) * 15 + (lx + dx)];
            if (ie >= 0) {
                int off = dy * 7 + dx;
                float wv = wk7[cq * 196 + ie * 49 + off] * khc[(ly + dy) * 15 + (lx + dx)];
                ka0 += (ie == 0) ? wv : 0.f;
                ka1 += (ie == 1) ? wv : 0.f;
                ka2 += (ie == 2) ? wv : 0.f;
                ka3 += (ie == 3) ? wv : 0.f;
                if (ie == ep) va += wv7[cq * 196 + ep * 49 + off] * vhc[(ly + dy) * 15 + (lx + dx)];
            }
        }
        kA[cq*256 + 0*64+t] = ka0; kA[cq*256 + 1*64+t] = ka1;
        kA[cq*256 + 2*64+t] = ka2; kA[cq*256 + 3*64+t] = ka3;
        vOwn[t * 33 + c] = va;
        __syncthreads();

        // ---- 8x8 circular convolution, own expert ----
        const float* qrow = &qA[cq * 256 + ep * 64];
        const float* krow = &kA[cq * 256 + ep * 64];
        float oc = 0.f;
#pragma unroll
        for (int sy = 0; sy < 8; ++sy) {
            int ky = ((ly - sy) & 7) * 8;
#pragma unroll
            for (int sx = 0; sx < 8; ++sx)
                oc += qrow[sy * 8 + sx] * krow[ky + ((lx - sx) & 7)];
        }
        oOwn[t * 33 + c] = oc;
        __syncthreads();
    }

    // ---- epilogue, parallel over cq ----
    // pool realias: svS [pix][65] @0 (4160), uS [pix][33] @4160 (2112)
    float* svS = pool;
    float* uS  = pool + 4160;

    for (int j = tid; j < 64 * 64; j += 256) {
        int c = j >> 6, pix = j & 63;
        int phw = (y0 + (pix >> 3)) * WW + x0 + (pix & 7);
        svS[pix * 65 + c] = shr[((size_t)(b * 64 + c)) * HWs + phw];
    }

    float o_[RK], vv_[RK];
#pragma unroll
    for (int c = 0; c < RK; ++c) { o_[c] = oOwn[t * 33 + c]; vv_[c] = vOwn[t * 33 + c]; }
    float mu = 0.f;
#pragma unroll
    for (int c = 0; c < RK; ++c) mu += o_[c];
    mu *= (1.0f / RK);
    float var = 0.f;
#pragma unroll
    for (int c = 0; c < RK; ++c) { float d = o_[c] - mu; var += d * d; }
    var *= (1.0f / RK);
    float inv = 1.0f / sqrtf(var + 1e-5f);
    float ttv[RK];
#pragma unroll
    for (int c = 0; c < RK; ++c)
        ttv[c] = ((o_[c] - mu) * inv * lnw[ep * RK + c] + lnb[ep * RK + c]) * vv_[c];

    const float g = gVal[base + hw];
    __syncthreads();   // svS ready

    // u rows r = cq*8 .. cq*8+7
    for (int r8 = 0; r8 < 8; ++r8) {
        int r = cq * 8 + r8;
        const float* wp1 = &p1w[(size_t)(ep * RK + r) * DIMc];
        float z = 0.f;
#pragma unroll
        for (int c = 0; c < DIMc; ++c) z += wp1[c] * svS[t * 65 + c];
        z *= g;
        float gate = z / (1.f + expf(-z));
        float bdy = fpb[ep * RK + r] + dot32(&fpw[(size_t)(ep * RK + r) * RK], ttv);
        uS[t * 33 + r] = bdy * gate;
    }
    __syncthreads();   // uS ready, svS dead

    // comb channels oo = cq*16 .. +15  (combS aliases svS region)
    float* combS = pool;
    for (int o16 = 0; o16 < 16; ++o16) {
        int oo = cq * 16 + o16;
        const float* wp2 = &p2w[(size_t)(ep * DIMc + oo) * RK];
        float a = 0.f;
#pragma unroll
        for (int r = 0; r < RK; ++r) a += wp2[r] * uS[t * 33 + r];
        float xv = x[((size_t)(b * DIMc + oo)) * HWs + hw];
        combS[t * 65 + oo] = g * a + g * g * xv;
    }
    __syncthreads();   // combS ready

    for (int o16 = 0; o16 < 16; ++o16) {
        int oo = cq * 16 + o16;
        const float* wo = &outw[oo * DIMc];
        float a = outb[oo];
#pragma unroll
        for (int c = 0; c < DIMc; ++c) a += wo[c] * combS[t * 65 + c];
        out[((size_t)(b * DIMc + oo)) * HWs + hw] = a;
    }
}

extern "C" void kernel_launch(void* const* d_in, const int* in_sizes, int n_in,
                              void* d_out, int out_size, void* d_ws, size_t ws_size,
                              hipStream_t stream) {
    const float* x    = (const float*)d_in[0];
    const float* shr  = (const float*)d_in[1];
    const float* rw   = (const float*)d_in[2];
    const float* rb_  = (const float*)d_in[3];
    const float* p0w  = (const float*)d_in[4];
    const float* p1w  = (const float*)d_in[5];
    const float* p2w  = (const float*)d_in[6];
    const float* qw   = (const float*)d_in[7];
    const float* qdw  = (const float*)d_in[8];
    const float* qdb  = (const float*)d_in[9];
    const float* kvw  = (const float*)d_in[10];
    const float* kvdw = (const float*)d_in[11];
    const float* kvdb = (const float*)d_in[12];
    const float* lnw  = (const float*)d_in[13];
    const float* lnb  = (const float*)d_in[14];
    const float* fpw  = (const float*)d_in[15];
    const float* fpb  = (const float*)d_in[16];
    const float* outw = (const float*)d_in[17];
    const float* outb = (const float*)d_in[18];
    float* out = (float*)d_out;

    const int N = 4 * HWs;
    char* ws = (char*)d_ws;
    int*   eIdx  = (int*)ws;            ws += (size_t)N * sizeof(int);
    float* gV    = (float*)ws;          ws += (size_t)N * sizeof(float);
    float* qpre  = (float*)ws;          ws += (size_t)N * RK * sizeof(float);
    float* kvpre = (float*)ws;          ws += (size_t)N * 2 * RK * sizeof(float);

    k_router<<<N / 256, 256, 0, stream>>>(x, rw, rb_, p0w, qw, kvw, eIdx, gV, qpre, kvpre);
    k_patch<<<4 * 32 * 32, 256, 0, stream>>>(x, shr, eIdx, gV, qpre, kvpre,
                                             p1w, qdw, qdb, kvdw, kvdb,
                                             lnw, lnb, fpw, fpb, p2w, outw, outb, out);
}